// Round 2
// baseline (1154.681 us; speedup 1.0000x reference)
//
#include <hip/hip_runtime.h>

#define NV   200000      // occupied voxels
#define CC   128         // channels
#define KOFF 27          // 3x3x3 offsets

typedef unsigned short u16;
typedef __attribute__((ext_vector_type(4))) float f32x4;
typedef __attribute__((ext_vector_type(8))) short bf16x8;

__device__ __forceinline__ u16 f2bf(float f) {
    unsigned u = __float_as_uint(f);
    u += 0x7fffu + ((u >> 16) & 1u);          // RNE
    return (u16)(u >> 16);
}

// global -> LDS direct DMA, 16B per lane; LDS dest = uniform base + lane*16
#define GLOAD16(gp, lp)                                                        \
    __builtin_amdgcn_global_load_lds(                                          \
        (const __attribute__((address_space(1))) void*)(gp),                   \
        (__attribute__((address_space(3))) void*)(lp), 16, 0, 0)

// counted wait + scheduling fence (rule #18: pin VALU that consumes asm-loaded
// regs below the wait)
#define WAITV(n)                                                               \
    do {                                                                       \
        asm volatile("s_waitcnt vmcnt(" #n ")" ::: "memory");                  \
        __builtin_amdgcn_sched_barrier(0);                                     \
    } while (0)
#define BARRIER() asm volatile("s_barrier" ::: "memory")

// ---------------------------------------------------------------------------
// gmap[k][i] = input row feeding output row i at offset k, or -1.
// out_idx entries are distinct per k, so this scatter is race-free.
__global__ void gmap_kernel(const int* __restrict__ iin,
                            const int* __restrict__ iout,
                            int* __restrict__ gmap) {
    int t = blockIdx.x * 256 + threadIdx.x;
    if (t >= KOFF * NV) return;
    int o = iout[t];
    if (o < NV) {
        int k = t / NV;
        gmap[k * NV + o] = iin[t];
    }
}

// fp32 -> bf16, 4 elems/thread
__global__ void cvt_kernel(const float* __restrict__ src,
                           u16* __restrict__ dst, int n4) {
    int i = blockIdx.x * 256 + threadIdx.x;
    if (i >= n4) return;
    float4 v = ((const float4*)src)[i];
    ushort4 o;
    o.x = f2bf(v.x); o.y = f2bf(v.y); o.z = f2bf(v.z); o.w = f2bf(v.w);
    ((ushort4*)dst)[i] = o;
}

// Pack W[k][kpos][col] fp32 into fragment-linear bf16:
// Wp[(k*nks+ks)*8 + cf][lane][j] = W[k][ks*32 + (lane>>4)*8 + j][cf*16 + (lane&15)]
__global__ void packw_kernel(const float* __restrict__ W,
                             u16* __restrict__ Wp, int cin, int total) {
    int t = blockIdx.x * 256 + threadIdx.x;
    if (t >= total) return;
    int j  = t & 7;
    int l  = (t >> 3) & 63;
    int cf = (t >> 9) & 7;
    int sk = t >> 12;                 // k*nks + ks
    int nks = cin >> 5;
    int k  = sk / nks;
    int ks = sk - k * nks;
    int kpos = ks * 32 + (l >> 4) * 8 + j;
    int col  = cf * 16 + (l & 15);
    Wp[t] = f2bf(W[((size_t)k * cin + kpos) * CC + col]);
}

// ---------------------------------------------------------------------------
// Gathered sparse conv: out[i] = bias + sum_k feat[gmap[k][i]] @ W[k]
// 256x128 tile / block, 8 waves (64x64 each), BK=64, 3-deep LDS pipeline
// with counted vmcnt (never drains in main loop), raw s_barrier (no drain).
template <int NKT, int ACT, int OUT16>
__global__ __launch_bounds__(512, 2)
void conv_kernel(const u16* __restrict__ f0, const u16* __restrict__ f1,
                 const u16* __restrict__ Wp, const float* __restrict__ bias,
                 const int* __restrict__ gmap, const u16* __restrict__ zrow,
                 float* __restrict__ out32, u16* __restrict__ out16) {
    constexpr int NT = KOFF * NKT;          // 54 or 108 K-tiles of 64

    __shared__ u16 Ab[3][256 * 64];         // 3 x 32 KiB, chunk-swizzled
    __shared__ u16 Bb[3][16 * 512];         // 3 x 16 KiB, fragment-linear

    const int tid = threadIdx.x;
    const int l   = tid & 63;
    const int w   = tid >> 6;               // 8 waves
    const int wr  = w >> 1, wc = w & 1;     // 4M x 2N
    const int r0  = blockIdx.x * 256;

    const int lrow8 = l >> 3;               // row within 8-row group
    const int csw   = (l & 7) ^ lrow8;      // pre-swizzled source chunk
    const u16* zsrc = zrow + csw * 8;

    int rowIdx[4];                          // fixed gather rows per A-instr
#pragma unroll
    for (int i = 0; i < 4; ++i) rowIdx[i] = r0 + i * 64 + w * 8 + lrow8;

    float bcol[4];
#pragma unroll
    for (int n = 0; n < 4; ++n) bcol[n] = bias[wc * 64 + n * 16 + (l & 15)];

    f32x4 acc[4][4] = {};

    int gmA[4], gmB[4];                     // gather rows, asm-loaded,
                                            // valid only after counted vmcnt
    auto loadGm = [&](int t, int* gm) {
        int k = t / NKT;
        const int* base = gmap + (size_t)k * NV;
#pragma unroll
        for (int i = 0; i < 4; ++i) {
            const int* p = base + rowIdx[i];
            asm volatile("global_load_dword %0, %1, off"
                         : "=v"(gm[i]) : "v"(p) : "memory");
        }
    };

    auto stage = [&](int t, int buf, const int* gm) {
        int k = t / NKT, kt = t % NKT;
        const u16* fb;
        int coloff;
        if constexpr (NKT == 4) {           // concat: kt 0,1 = x, kt 2,3 = h
            fb = (kt < 2) ? f0 : f1;  coloff = (kt & 1) * 64;
        } else {
            fb = f0;                  coloff = kt * 64;
        }
#pragma unroll
        for (int i = 0; i < 4; ++i) {
            int g = gm[i];
            const u16* src = (g >= 0)
                ? fb + ((size_t)g << 7) + coloff + csw * 8 : zsrc;
            GLOAD16(src, &Ab[buf][(i * 64 + w * 8) * 64]);
        }
        const u16* wsrc = Wp + ((size_t)(k * (2 * NKT) + kt * 2) * 8) * 512 + l * 8;
        GLOAD16(wsrc + (size_t)w * 512,       &Bb[buf][w * 512]);
        GLOAD16(wsrc + (size_t)(8 + w) * 512, &Bb[buf][(8 + w) * 512]);
    };

    auto compute = [&](int buf) {
        bf16x8 a[2][4], b[2][4];
#pragma unroll
        for (int ks = 0; ks < 2; ++ks) {
#pragma unroll
            for (int m = 0; m < 4; ++m) {
                int row = wr * 64 + m * 16 + (l & 15);
                int ch  = (ks * 4 + (l >> 4)) ^ (row & 7);
                a[ks][m] = *(const bf16x8*)&Ab[buf][row * 64 + ch * 8];
            }
#pragma unroll
            for (int n = 0; n < 4; ++n)
                b[ks][n] = *(const bf16x8*)&Bb[buf][(ks * 8 + wc * 4 + n) * 512 + l * 8];
        }
        __builtin_amdgcn_s_setprio(1);
#pragma unroll
        for (int ks = 0; ks < 2; ++ks)
#pragma unroll
            for (int m = 0; m < 4; ++m)
#pragma unroll
                for (int n = 0; n < 4; ++n)
                    acc[m][n] = __builtin_amdgcn_mfma_f32_16x16x32_bf16(
                        a[ks][m], b[ks][n], acc[m][n], 0, 0, 0);
        __builtin_amdgcn_s_setprio(0);
    };

    // prologue: establish 2-tiles-ahead pipeline (NT >= 4 always)
    loadGm(0, gmA);
    WAITV(0);                                // gm(0) ready
    loadGm(1, gmB);                          // issue BEFORE stage(0)
    stage(0, 0, gmA);
    WAITV(6);                                // gm(1) ready, stage(0) in flight
    loadGm(2, gmA);
    stage(1, 1, gmB);
    // in flight: stage(0) 6, gm(2) 4, stage(1) 6

    int cur = 0, sb = 2;
    // parity-unrolled main loop (NT even): gmA/gmB alternate, no runtime
    // array selection (rule #20)
    for (int tp = 0; tp < NT; tp += 2) {
        {   // even t: consume gmA, refill gmB
            int t = tp;
            if (t + 2 < NT) {
                WAITV(6);                    // tile t + gm(t+2) done; t+1 in flight
                if (t + 3 < NT) loadGm(t + 3, gmB);
                stage(t + 2, sb, gmA);
            } else if (t + 1 < NT) { WAITV(6); }
            else                   { WAITV(0); }
            BARRIER();
            compute(cur);
            BARRIER();
            cur = (cur == 2) ? 0 : cur + 1;
            sb  = (sb  == 2) ? 0 : sb  + 1;
        }
        {   // odd t: consume gmB, refill gmA
            int t = tp + 1;
            if (t + 2 < NT) {
                WAITV(6);
                if (t + 3 < NT) loadGm(t + 3, gmA);
                stage(t + 2, sb, gmB);
            } else if (t + 1 < NT) { WAITV(6); }
            else                   { WAITV(0); }
            BARRIER();
            compute(cur);
            BARRIER();
            cur = (cur == 2) ? 0 : cur + 1;
            sb  = (sb  == 2) ? 0 : sb  + 1;
        }
    }

    // epilogue: C/D layout col=lane&15, row=(lane>>4)*4+reg  [m89-verified]
#pragma unroll
    for (int m = 0; m < 4; ++m) {
        int rbase = r0 + wr * 64 + m * 16 + (l >> 4) * 4;
#pragma unroll
        for (int i = 0; i < 4; ++i) {
            int row = rbase + i;
            if (row < NV) {
#pragma unroll
                for (int n = 0; n < 4; ++n) {
                    float v = acc[m][n][i] + bcol[n];
                    if constexpr (ACT) v = fmaxf(v, 0.f);
                    int col = wc * 64 + n * 16 + (l & 15);
                    if constexpr (OUT16) out16[(size_t)row * CC + col] = f2bf(v);
                    else                 out32[(size_t)row * CC + col] = v;
                }
            }
        }
    }
}

// ---------------------------------------------------------------------------
extern "C" void kernel_launch(void* const* d_in, const int* in_sizes, int n_in,
                              void* d_out, int out_size, void* d_ws, size_t ws_size,
                              hipStream_t stream) {
    (void)in_sizes; (void)n_in; (void)out_size; (void)ws_size;
    const float* xF  = (const float*)d_in[0];
    const float* xgF = (const float*)d_in[1];
    const float* W0  = (const float*)d_in[2];
    const float* b0  = (const float*)d_in[3];
    const float* W1  = (const float*)d_in[4];
    const float* b1  = (const float*)d_in[5];
    const float* W2  = (const float*)d_in[6];
    const float* b2  = (const float*)d_in[7];
    const int* iin   = (const int*)d_in[8];
    const int* iout  = (const int*)d_in[9];
    float* out = (float*)d_out;
    char* ws = (char*)d_ws;

    size_t off = 0;
    int* gmap  = (int*)(ws + off);  off += ((size_t)KOFF * NV + 512) * 4;  // +pad rows (-1)
    u16* zrow  = (u16*)(ws + off);  off += 256;
    u16* F0    = (u16*)(ws + off);  off += (size_t)NV * CC * 2;     // xg16 -> h1
    u16* F1    = (u16*)(ws + off);  off += (size_t)NV * CC * 2;     // h0
    u16* F2    = (u16*)(ws + off);  off += (size_t)NV * CC * 2;     // x16
    u16* WP0   = (u16*)(ws + off);  off += (size_t)KOFF * 128 * 128 * 2;
    u16* WP1   = (u16*)(ws + off);  off += (size_t)KOFF * 128 * 128 * 2;
    u16* WP2   = (u16*)(ws + off);  off += (size_t)KOFF * 256 * 128 * 2;
    // total ~178.7 MB of d_ws

    (void)hipMemsetAsync(gmap, 0xFF, ((size_t)KOFF * NV + 512) * 4, stream);  // -1
    (void)hipMemsetAsync(zrow, 0, 256, stream);

    gmap_kernel<<<(KOFF * NV + 255) / 256, 256, 0, stream>>>(iin, iout, gmap);
    cvt_kernel<<<(NV * CC / 4 + 255) / 256, 256, 0, stream>>>(xgF, F0, NV * CC / 4);
    cvt_kernel<<<(NV * CC / 4 + 255) / 256, 256, 0, stream>>>(xF,  F2, NV * CC / 4);
    packw_kernel<<<(KOFF * 128 * 128 + 255) / 256, 256, 0, stream>>>(W0, WP0, 128, KOFF * 128 * 128);
    packw_kernel<<<(KOFF * 128 * 128 + 255) / 256, 256, 0, stream>>>(W1, WP1, 128, KOFF * 128 * 128);
    packw_kernel<<<(KOFF * 256 * 128 + 255) / 256, 256, 0, stream>>>(W2, WP2, 256, KOFF * 256 * 128);

    const int NB = (NV + 255) / 256;   // 782
    // conv0: h0 = xg (*) W0 + b0            -> F1 (bf16)
    conv_kernel<2, 0, 1><<<NB, 512, 0, stream>>>(F0, F0, WP0, b0, gmap, zrow, nullptr, F1);
    // conv1: h1 = relu(h0 (*) W1 + b1)      -> F0 (bf16)
    conv_kernel<2, 1, 1><<<NB, 512, 0, stream>>>(F1, F1, WP1, b1, gmap, zrow, nullptr, F0);
    // conv2: out = [x | h1] (*) W2 + b2     -> d_out (fp32)
    conv_kernel<4, 0, 0><<<NB, 512, 0, stream>>>(F2, F0, WP2, b2, gmap, zrow, out, nullptr);
}